// Round 1
// baseline (756.541 us; speedup 1.0000x reference)
//
#include <hip/hip_runtime.h>

// CustomGNN on MI355X. Pipeline per call:
//   sort edges by (type, tgt) -> 3x [edge-MLP (bf16 MFMA) + scatter-add + GRU (bf16 MFMA)] -> readout.
// All matmuls bf16 MFMA 16x16x32 with fp32 accumulate; h kept in fp32 + bf16 mirror.

#define NN 50000
#define EE 640000
#define HH 128
#define NBINS (2 * NN)
#define NTILES (EE / 64) // 10000

typedef __attribute__((ext_vector_type(8))) short short8;
typedef __attribute__((ext_vector_type(4))) float f32x4;

__device__ __forceinline__ unsigned short f2b(float f) {
  union { float f; unsigned int u; } a; a.f = f;
  unsigned int u = a.u;
  unsigned int r = (u + 0x7FFFu + ((u >> 16) & 1u)) >> 16;
  if ((u & 0x7F800000u) == 0x7F800000u) r = u >> 16; // inf/nan passthrough
  return (unsigned short)r;
}

// ---------- init: h = x (fp32) and bf16 mirror ----------
__global__ __launch_bounds__(256) void k_init(const float* __restrict__ x, float* __restrict__ h,
                                              unsigned short* __restrict__ hbf) {
  int i = blockIdx.x * 256 + threadIdx.x; // grid exact
  float v = x[i];
  h[i] = v;
  hbf[i] = f2b(v);
}

// ---------- pack weights into MFMA B-fragment order (bf16) ----------
// B-frag (16x16x32): lane l holds B[k = ks*32 + (l>>4)*8 + j][col = nt*16 + (l&15)], j=0..7
__global__ __launch_bounds__(256) void k_pack(
    const float* __restrict__ w1s, const float* __restrict__ w2s,
    const float* __restrict__ w1f, const float* __restrict__ w2f,
    const float* __restrict__ gwih, const float* __restrict__ gwhh,
    const float* __restrict__ gbih, const float* __restrict__ gbhh,
    unsigned short* __restrict__ pw1s, unsigned short* __restrict__ pw2s,
    unsigned short* __restrict__ pw1f, unsigned short* __restrict__ pw2f,
    unsigned short* __restrict__ pgru, float* __restrict__ bgr) {
  int i = blockIdx.x * 256 + threadIdx.x;
  if (i < 65536) { // pW1 (2 types x 32768): [256][128]
    int ty = i >> 15, idx = i & 32767;
    int j = idx & 7, l = (idx >> 3) & 63, kn = idx >> 9;
    int ks = kn & 7, nt = kn >> 3;
    int k = ks * 32 + (l >> 4) * 8 + j, c = nt * 16 + (l & 15);
    const float* w = ty ? w1f : w1s;
    (ty ? pw1f : pw1s)[idx] = f2b(w[k * 128 + c]);
  } else if (i < 98304) { // pW2 (2 types x 16384): [128][128]
    int i2 = i - 65536;
    int ty = i2 >> 14, idx = i2 & 16383;
    int j = idx & 7, l = (idx >> 3) & 63, kn = idx >> 9;
    int ks = kn & 3, nt = kn >> 2;
    int k = ks * 32 + (l >> 4) * 8 + j, c = nt * 16 + (l & 15);
    const float* w = ty ? w2f : w2s;
    (ty ? pw2f : pw2s)[idx] = f2b(w[k * 128 + c]);
  } else if (i < 98304 + 131072) { // pGRU: B[256][512] with zero blocks
    int idx = i - 98304;
    int j = idx & 7, l = (idx >> 3) & 63, kc = idx >> 9;
    int ks = kc & 7, ct = kc >> 3;
    int k = ks * 32 + (l >> 4) * 8 + j, c = ct * 16 + (l & 15);
    float v;
    if (c < 256)      v = (k < 128) ? gwih[c * 128 + k] : gwhh[c * 128 + (k - 128)];
    else if (c < 384) v = (k < 128) ? gwih[c * 128 + k] : 0.f;  // gi_n part
    else              v = (k >= 128) ? gwhh[(c - 128) * 128 + (k - 128)] : 0.f; // gh_n part
    pgru[idx] = f2b(v);
  } else if (i < 98304 + 131072 + 512) { // fused GRU biases
    int j = i - (98304 + 131072);
    float v;
    if (j < 256)      v = gbih[j] + gbhh[j]; // r and z: b_ih + b_hh
    else if (j < 384) v = gbih[j];           // gi_n bias
    else              v = gbhh[j - 128];     // gh_n bias
    bgr[j] = v;
  }
}

// ---------- histogram over key = type*NN + tgt ----------
__global__ __launch_bounds__(256) void k_hist(const int* __restrict__ ei, const int* __restrict__ et,
                                              int* __restrict__ hist) {
  int e = blockIdx.x * 256 + threadIdx.x; // grid exact
  int g = ei[EE + e];
  int ty = et[e];
  atomicAdd(&hist[ty * NN + g], 1);
}

// ---------- exclusive scan (3 kernels) ----------
__global__ __launch_bounds__(1024) void k_scan1(const int* __restrict__ hist, int* __restrict__ base,
                                                int* __restrict__ bsum) {
  __shared__ int sh[1024];
  int t = threadIdx.x;
  int i = blockIdx.x * 1024 + t;
  int v = (i < NBINS) ? hist[i] : 0;
  sh[t] = v;
  __syncthreads();
  for (int o = 1; o < 1024; o <<= 1) {
    int xv = (t >= o) ? sh[t - o] : 0;
    __syncthreads();
    sh[t] += xv;
    __syncthreads();
  }
  if (i < NBINS) base[i] = sh[t] - v;
  if (t == 1023) bsum[blockIdx.x] = sh[t];
}

__global__ __launch_bounds__(128) void k_scan2(int* __restrict__ bsum) {
  __shared__ int sh[128];
  int t = threadIdx.x;
  int v = (t < 98) ? bsum[t] : 0;
  sh[t] = v;
  __syncthreads();
  for (int o = 1; o < 128; o <<= 1) {
    int xv = (t >= o) ? sh[t - o] : 0;
    __syncthreads();
    sh[t] += xv;
    __syncthreads();
  }
  if (t < 98) bsum[t] = sh[t] - v;
}

__global__ __launch_bounds__(1024) void k_scan3(const int* __restrict__ bsum, int* __restrict__ base,
                                                int* __restrict__ cnt) {
  int i = blockIdx.x * 1024 + threadIdx.x;
  if (i < NBINS) {
    int b = base[i] + bsum[blockIdx.x];
    base[i] = b;
    if (i == NN) cnt[0] = b; // count of type-0 edges
  }
}

// ---------- scatter into sorted order ----------
__global__ __launch_bounds__(256) void k_scatter(const int* __restrict__ ei, const int* __restrict__ et,
                                                 int* __restrict__ woff, int* __restrict__ ssrc,
                                                 int* __restrict__ stgt) {
  int e = blockIdx.x * 256 + threadIdx.x; // grid exact
  int s = ei[e], g = ei[EE + e], ty = et[e];
  int pos = atomicAdd(&woff[ty * NN + g], 1);
  ssrc[pos] = s;
  stgt[pos] = g;
}

// ---------- edge MLP + segment scatter-add ----------
// tile = 64 edges, 256 threads / 4 waves. A-frag row = l&15, k = ks*32+(l>>4)*8+j.
// LDS XOR swizzle: byte ^= (row&7)<<4 (kills stride-512B bank conflicts).
__global__ __launch_bounds__(256) void k_edge(
    const unsigned short* __restrict__ hbf,
    const int* __restrict__ ssrc, const int* __restrict__ stgt,
    const unsigned short* __restrict__ pw1s, const unsigned short* __restrict__ pw2s,
    const unsigned short* __restrict__ pw1f, const unsigned short* __restrict__ pw2f,
    const float* __restrict__ b1s, const float* __restrict__ b2s,
    const float* __restrict__ b1f, const float* __restrict__ b2f,
    float* __restrict__ msg, const int* __restrict__ cnt) {
  __shared__ char efb[64 * 512];   // ef bf16 [64][256] swz; reused as m f32 [64][128] swz
  __shared__ char hidb[64 * 256];  // hidden bf16 [64][128] swz
  __shared__ int tsrc[64];
  __shared__ int ttgt[64];
  int tid = threadIdx.x;
  int l = tid & 63, w = tid >> 6;
  int c0 = cnt[0];
  int bid = blockIdx.x;
  int type = (bid >= NTILES) ? 1 : 0;
  int tb = type ? (bid - NTILES) : bid;
  int lo = type ? c0 : 0;
  int hi = type ? EE : c0;
  int start = lo + tb * 64;
  if (start >= hi) return;
  const unsigned short* pw1 = type ? pw1f : pw1s;
  const unsigned short* pw2 = type ? pw2f : pw2s;
  const float* b1 = type ? b1f : b1s;
  const float* b2 = type ? b2f : b2s;

  if (tid < 64) {
    int pp = start + tid;
    int s = 0, g = -1;
    if (pp < hi) { s = ssrc[pp]; g = stgt[pp]; }
    tsrc[tid] = (s < 0) ? 0 : s;
    ttgt[tid] = g;
  }
  __syncthreads();

  // gather ef = [h[src] | h[tgt]] (bf16), 16B chunks, swizzled LDS
#pragma unroll
  for (int i = 0; i < 8; i++) {
    int c = tid + i * 256;            // 2048 chunks = 64 rows x 32
    int r = c >> 5, cc = c & 31;
    int gv = ttgt[r];
    int node = (cc < 16) ? tsrc[r] : (gv < 0 ? 0 : gv);
    int4 v = *((const int4*)(hbf + (size_t)node * HH) + (cc & 15));
    *(int4*)(efb + r * 512 + ((cc * 16) ^ ((r & 7) << 4))) = v;
  }
  __syncthreads();

  // GEMM1: [64x256] @ W1[256x128]
  short8 bf1[2][8];
#pragma unroll
  for (int q = 0; q < 2; q++) {
    int nt = 2 * w + q;
#pragma unroll
    for (int ks = 0; ks < 8; ks++)
      bf1[q][ks] = *(const short8*)(pw1 + ((nt * 8 + ks) * 64 + l) * 8);
  }
  f32x4 zero4 = {0.f, 0.f, 0.f, 0.f};
  f32x4 acc[4][2];
#pragma unroll
  for (int mt = 0; mt < 4; mt++)
#pragma unroll
    for (int q = 0; q < 2; q++) acc[mt][q] = zero4;
#pragma unroll
  for (int ks = 0; ks < 8; ks++) {
    short8 a[4];
#pragma unroll
    for (int mt = 0; mt < 4; mt++) {
      int row = mt * 16 + (l & 15);
      a[mt] = *(const short8*)(efb + row * 512 + ((ks * 64 + (l >> 4) * 16) ^ ((row & 7) << 4)));
    }
#pragma unroll
    for (int mt = 0; mt < 4; mt++)
#pragma unroll
      for (int q = 0; q < 2; q++)
        acc[mt][q] = __builtin_amdgcn_mfma_f32_16x16x32_bf16(a[mt], bf1[q][ks], acc[mt][q], 0, 0, 0);
  }

  // bias + relu -> hidden (bf16, swizzled LDS). C layout: col=l&15(+16*nt), row=(l>>4)*4+r(+16*mt)
  float b1v[2];
  b1v[0] = b1[(2 * w) * 16 + (l & 15)];
  b1v[1] = b1[(2 * w + 1) * 16 + (l & 15)];
#pragma unroll
  for (int mt = 0; mt < 4; mt++)
#pragma unroll
    for (int q = 0; q < 2; q++) {
      int col = (2 * w + q) * 16 + (l & 15);
#pragma unroll
      for (int r = 0; r < 4; r++) {
        int row = mt * 16 + (l >> 4) * 4 + r;
        float v = acc[mt][q][r] + b1v[q];
        v = v > 0.f ? v : 0.f;
        *(unsigned short*)(hidb + row * 256 + ((col * 2) ^ ((row & 7) << 4))) = f2b(v);
      }
    }
  __syncthreads();

  // GEMM2: hidden[64x128] @ W2[128x128]
  short8 bf2[2][4];
#pragma unroll
  for (int q = 0; q < 2; q++) {
    int nt = 2 * w + q;
#pragma unroll
    for (int ks = 0; ks < 4; ks++)
      bf2[q][ks] = *(const short8*)(pw2 + ((nt * 4 + ks) * 64 + l) * 8);
  }
  f32x4 acc2[4][2];
#pragma unroll
  for (int mt = 0; mt < 4; mt++)
#pragma unroll
    for (int q = 0; q < 2; q++) acc2[mt][q] = zero4;
#pragma unroll
  for (int ks = 0; ks < 4; ks++) {
    short8 a[4];
#pragma unroll
    for (int mt = 0; mt < 4; mt++) {
      int row = mt * 16 + (l & 15);
      a[mt] = *(const short8*)(hidb + row * 256 + ((ks * 64 + (l >> 4) * 16) ^ ((row & 7) << 4)));
    }
#pragma unroll
    for (int mt = 0; mt < 4; mt++)
#pragma unroll
      for (int q = 0; q < 2; q++)
        acc2[mt][q] = __builtin_amdgcn_mfma_f32_16x16x32_bf16(a[mt], bf2[q][ks], acc2[mt][q], 0, 0, 0);
  }

  // m (+b2) -> LDS f32 [64][128] swz (reuse efb; safe: all GEMM1 reads done before hid barrier)
  float b2v[2];
  b2v[0] = b2[(2 * w) * 16 + (l & 15)];
  b2v[1] = b2[(2 * w + 1) * 16 + (l & 15)];
#pragma unroll
  for (int mt = 0; mt < 4; mt++)
#pragma unroll
    for (int q = 0; q < 2; q++) {
      int col = (2 * w + q) * 16 + (l & 15);
#pragma unroll
      for (int r = 0; r < 4; r++) {
        int row = mt * 16 + (l >> 4) * 4 + r;
        *(float*)(efb + row * 512 + ((col * 4) ^ ((row & 7) << 4))) = acc2[mt][q][r] + b2v[q];
      }
    }
  __syncthreads();

  // segment-reduce runs of equal tgt (tile sorted by tgt) then atomicAdd once per (run, feature)
  int f = tid & 127;
  int e0 = (tid >> 7) * 32;
  float accum = 0.f;
  int cur = ttgt[e0];
  for (int e = e0; e < e0 + 32; e++) {
    int g = ttgt[e];
    float v = *(const float*)(efb + e * 512 + ((f * 4) ^ ((e & 7) << 4)));
    if (g != cur) {
      if (cur >= 0) atomicAdd(&msg[(size_t)cur * HH + f], accum);
      accum = 0.f;
      cur = g;
    }
    accum += v;
  }
  if (cur >= 0) atomicAdd(&msg[(size_t)cur * HH + f], accum);
}

// ---------- GRU update: [m|h](64x256) @ B(256x512), col-tiles interleaved so r/z/gin/ghn share a lane
__global__ __launch_bounds__(256) void k_gru(
    const float* __restrict__ msg, const unsigned short* __restrict__ pgru,
    const float* __restrict__ bgr, float* __restrict__ h, unsigned short* __restrict__ hbf) {
  __shared__ char amh[64 * 512]; // [64][256] bf16 swz
  int tid = threadIdx.x, l = tid & 63, w = tid >> 6;
  int n0 = blockIdx.x * 64;
  // stage m (k 0..127), fp32 -> bf16
#pragma unroll
  for (int i = 0; i < 8; i++) {
    int c = tid + i * 256;
    int r = c >> 5, cc = c & 31;
    int node = n0 + r; if (node > NN - 1) node = NN - 1;
    float4 v = *((const float4*)(msg + (size_t)node * HH) + cc);
    uint2 u;
    u.x = (unsigned int)f2b(v.x) | ((unsigned int)f2b(v.y) << 16);
    u.y = (unsigned int)f2b(v.z) | ((unsigned int)f2b(v.w) << 16);
    *(uint2*)(amh + r * 512 + ((cc * 8) ^ ((r & 7) << 4))) = u;
  }
  // stage h (k 128..255), bf16 copy
#pragma unroll
  for (int i = 0; i < 4; i++) {
    int c = tid + i * 256;
    int r = c >> 4, cc = c & 15;
    int node = n0 + r; if (node > NN - 1) node = NN - 1;
    int4 v = *((const int4*)(hbf + (size_t)node * HH) + cc);
    *(int4*)(amh + r * 512 + ((256 + cc * 16) ^ ((r & 7) << 4))) = v;
  }
  __syncthreads();

  f32x4 zero4 = {0.f, 0.f, 0.f, 0.f};
  f32x4 acc[4][8];
#pragma unroll
  for (int mt = 0; mt < 4; mt++)
#pragma unroll
    for (int t = 0; t < 8; t++) acc[mt][t] = zero4;
#pragma unroll
  for (int ks = 0; ks < 8; ks++) {
    short8 a[4];
#pragma unroll
    for (int mt = 0; mt < 4; mt++) {
      int row = mt * 16 + (l & 15);
      a[mt] = *(const short8*)(amh + row * 512 + ((ks * 64 + (l >> 4) * 16) ^ ((row & 7) << 4)));
    }
#pragma unroll
    for (int t = 0; t < 8; t++) {
      int ct = w + 4 * t;
      short8 bf = *(const short8*)(pgru + ((ct * 8 + ks) * 64 + l) * 8);
#pragma unroll
      for (int mt = 0; mt < 4; mt++)
        acc[mt][t] = __builtin_amdgcn_mfma_f32_16x16x32_bf16(a[mt], bf, acc[mt][t], 0, 0, 0);
    }
  }

  // gates fully in-register: acc[.][tt]=u_r, [tt+2]=u_z, [tt+4]=gi_n, [tt+6]=gh_n
#pragma unroll
  for (int tt = 0; tt < 2; tt++) {
    int ct = w + 4 * tt;
    int j = ct * 16 + (l & 15);
    float br = bgr[j], bz = bgr[128 + j], bgi = bgr[256 + j], bgh = bgr[384 + j];
#pragma unroll
    for (int mt = 0; mt < 4; mt++) {
#pragma unroll
      for (int r = 0; r < 4; r++) {
        int row = mt * 16 + (l >> 4) * 4 + r;
        int node = n0 + row;
        if (node < NN) {
          float hold = h[(size_t)node * HH + j];
          float ur = acc[mt][tt][r] + br;
          float uz = acc[mt][tt + 2][r] + bz;
          float gi = acc[mt][tt + 4][r] + bgi;
          float gh = acc[mt][tt + 6][r] + bgh;
          float rr = 1.f / (1.f + __expf(-ur));
          float zz = 1.f / (1.f + __expf(-uz));
          float xx = gi + rr * gh;
          xx = fminf(fmaxf(xx, -15.f), 15.f);
          float ex = __expf(2.f * xx);
          float nn2 = (ex - 1.f) / (ex + 1.f); // tanh
          float hn = (1.f - zz) * nn2 + zz * hold;
          h[(size_t)node * HH + j] = hn;
          hbf[(size_t)node * HH + j] = f2b(hn);
        }
      }
    }
  }
}

// ---------- readout: softmax(relu(h@wr1+br1)@wr2+br2), vector fp32 ----------
__global__ __launch_bounds__(256) void k_read(const float* __restrict__ h,
                                              const float* __restrict__ wr1, const float* __restrict__ br1,
                                              const float* __restrict__ wr2, const float* __restrict__ br2,
                                              float* __restrict__ out) {
  __shared__ float sh[16][128];
  int tid = threadIdx.x, l = tid & 63, w = tid >> 6;
  int nb = blockIdx.x * 16;
#pragma unroll
  for (int i = 0; i < 8; i++) {
    int c = tid + i * 256;
    int r = c >> 7, k = c & 127;
    int node = nb + r; if (node > NN - 1) node = NN - 1;
    sh[r][k] = h[(size_t)node * HH + k];
  }
  __syncthreads();
  float a1[4] = {0.f, 0.f, 0.f, 0.f}, a2[4] = {0.f, 0.f, 0.f, 0.f};
  for (int k = 0; k < 128; k++) {
    float w1a = wr1[k * 128 + l];
    float w1b = wr1[k * 128 + l + 64];
#pragma unroll
    for (int n = 0; n < 4; n++) {
      float hv = sh[w * 4 + n][k];
      a1[n] += hv * w1a;
      a2[n] += hv * w1b;
    }
  }
  float bra = br1[l], brb = br1[l + 64];
  float w20 = wr2[l * 2 + 0], w21 = wr2[l * 2 + 1];
  float w20b = wr2[(l + 64) * 2 + 0], w21b = wr2[(l + 64) * 2 + 1];
#pragma unroll
  for (int n = 0; n < 4; n++) {
    float h1 = fmaxf(a1[n] + bra, 0.f), h2 = fmaxf(a2[n] + brb, 0.f);
    float l0 = h1 * w20 + h2 * w20b;
    float l1 = h1 * w21 + h2 * w21b;
#pragma unroll
    for (int o = 32; o > 0; o >>= 1) {
      l0 += __shfl_xor(l0, o);
      l1 += __shfl_xor(l1, o);
    }
    if (l == 0) {
      int node = nb + w * 4 + n;
      if (node < NN) {
        l0 += br2[0];
        l1 += br2[1];
        float mx = fmaxf(l0, l1);
        float e0 = __expf(l0 - mx), e1 = __expf(l1 - mx);
        float s = e0 + e1;
        out[node * 2 + 0] = e0 / s;
        out[node * 2 + 1] = e1 / s;
      }
    }
  }
}

extern "C" void kernel_launch(void* const* d_in, const int* in_sizes, int n_in,
                              void* d_out, int out_size, void* d_ws, size_t ws_size,
                              hipStream_t stream) {
  const float* x    = (const float*)d_in[0];
  const int*   ei   = (const int*)d_in[1];
  const int*   et   = (const int*)d_in[2];
  const float* w1s  = (const float*)d_in[3];
  const float* b1s  = (const float*)d_in[4];
  const float* w2s  = (const float*)d_in[5];
  const float* b2s  = (const float*)d_in[6];
  const float* w1f  = (const float*)d_in[7];
  const float* b1f  = (const float*)d_in[8];
  const float* w2f  = (const float*)d_in[9];
  const float* b2f  = (const float*)d_in[10];
  const float* gwih = (const float*)d_in[11];
  const float* gwhh = (const float*)d_in[12];
  const float* gbih = (const float*)d_in[13];
  const float* gbhh = (const float*)d_in[14];
  const float* wr1  = (const float*)d_in[15];
  const float* br1  = (const float*)d_in[16];
  const float* wr2  = (const float*)d_in[17];
  const float* br2  = (const float*)d_in[18];
  float* out = (float*)d_out;
  (void)in_sizes; (void)n_in; (void)out_size; (void)ws_size;

  char* p = (char*)d_ws;
  size_t off = 0;
  auto alloc = [&](size_t sz) {
    char* r = p + off;
    off = (off + sz + 255) & ~(size_t)255;
    return r;
  };
  float* h             = (float*)alloc((size_t)NN * HH * 4);
  unsigned short* hbf  = (unsigned short*)alloc((size_t)NN * HH * 2);
  float* msg           = (float*)alloc((size_t)NN * HH * 4);
  int* ssrc            = (int*)alloc((size_t)(EE + 64) * 4);
  int* stgt            = (int*)alloc((size_t)(EE + 64) * 4);
  int* hist            = (int*)alloc((size_t)NBINS * 4);
  int* base            = (int*)alloc((size_t)NBINS * 4);
  int* woff            = (int*)alloc((size_t)NBINS * 4);
  int* bsum            = (int*)alloc(128 * 4);
  int* cnt             = (int*)alloc(16);
  unsigned short* pw1s = (unsigned short*)alloc(32768 * 2);
  unsigned short* pw2s = (unsigned short*)alloc(16384 * 2);
  unsigned short* pw1f = (unsigned short*)alloc(32768 * 2);
  unsigned short* pw2f = (unsigned short*)alloc(16384 * 2);
  unsigned short* pgru = (unsigned short*)alloc(131072 * 2);
  float* bgr           = (float*)alloc(512 * 4);

  hipMemsetAsync(hist, 0, (size_t)NBINS * 4, stream);
  k_init<<<NN * HH / 256, 256, 0, stream>>>(x, h, hbf);
  k_pack<<<898, 256, 0, stream>>>(w1s, w2s, w1f, w2f, gwih, gwhh, gbih, gbhh,
                                  pw1s, pw2s, pw1f, pw2f, pgru, bgr);
  k_hist<<<EE / 256, 256, 0, stream>>>(ei, et, hist);
  k_scan1<<<98, 1024, 0, stream>>>(hist, base, bsum);
  k_scan2<<<1, 128, 0, stream>>>(bsum);
  k_scan3<<<98, 1024, 0, stream>>>(bsum, base, cnt);
  hipMemcpyAsync(woff, base, (size_t)NBINS * 4, hipMemcpyDeviceToDevice, stream);
  k_scatter<<<EE / 256, 256, 0, stream>>>(ei, et, woff, ssrc, stgt);
  hipMemsetAsync(ssrc + EE, 0xFF, 64 * 4, stream); // pad sentinel (-1)
  hipMemsetAsync(stgt + EE, 0xFF, 64 * 4, stream);

  for (int layer = 0; layer < 3; layer++) {
    hipMemsetAsync(msg, 0, (size_t)NN * HH * 4, stream);
    k_edge<<<2 * NTILES, 256, 0, stream>>>(hbf, ssrc, stgt, pw1s, pw2s, pw1f, pw2f,
                                           b1s, b2s, b1f, b2f, msg, cnt);
    k_gru<<<(NN + 63) / 64, 256, 0, stream>>>(msg, pgru, bgr, h, hbf);
  }
  k_read<<<NN / 16, 256, 0, stream>>>(h, wr1, br1, wr2, br2, out);
}

// Round 2
// 624.937 us; speedup vs baseline: 1.2106x; 1.2106x over previous
//
#include <hip/hip_runtime.h>
#include <hip/hip_bf16.h>

// CustomGNN on MI355X. Pipeline per call:
//   sort edges by (type, tgt) -> 3x [edge-MLP (bf16 MFMA) + scatter-add + GRU (bf16 MFMA)] -> readout.
// R2: k_edge restructured — vectorized m^T LDS (b128 write+read), HW bf16 cvt,
//     K-split staging to cut LDS 48.5->33KB (3->4 blocks/CU).

#define NN 50000
#define EE 640000
#define HH 128
#define NBINS (2 * NN)
#define NTILES (EE / 64) // 10000

typedef __attribute__((ext_vector_type(8))) short short8;
typedef __attribute__((ext_vector_type(4))) float f32x4;

__device__ __forceinline__ unsigned short f2b(float f) {
  __hip_bfloat16 b = __float2bfloat16(f); // RNE, compiles to v_cvt_pk_bf16_f32
  return *reinterpret_cast<unsigned short*>(&b);
}

// ---------- init: h = x (fp32) and bf16 mirror ----------
__global__ __launch_bounds__(256) void k_init(const float* __restrict__ x, float* __restrict__ h,
                                              unsigned short* __restrict__ hbf) {
  int i = blockIdx.x * 256 + threadIdx.x; // grid exact
  float v = x[i];
  h[i] = v;
  hbf[i] = f2b(v);
}

// ---------- pack weights into MFMA B-fragment order (bf16) ----------
// B-frag (16x16x32): lane l holds B[k = ks*32 + (l>>4)*8 + j][col = nt*16 + (l&15)], j=0..7
__global__ __launch_bounds__(256) void k_pack(
    const float* __restrict__ w1s, const float* __restrict__ w2s,
    const float* __restrict__ w1f, const float* __restrict__ w2f,
    const float* __restrict__ gwih, const float* __restrict__ gwhh,
    const float* __restrict__ gbih, const float* __restrict__ gbhh,
    unsigned short* __restrict__ pw1s, unsigned short* __restrict__ pw2s,
    unsigned short* __restrict__ pw1f, unsigned short* __restrict__ pw2f,
    unsigned short* __restrict__ pgru, float* __restrict__ bgr) {
  int i = blockIdx.x * 256 + threadIdx.x;
  if (i < 65536) { // pW1 (2 types x 32768): [256][128]
    int ty = i >> 15, idx = i & 32767;
    int j = idx & 7, l = (idx >> 3) & 63, kn = idx >> 9;
    int ks = kn & 7, nt = kn >> 3;
    int k = ks * 32 + (l >> 4) * 8 + j, c = nt * 16 + (l & 15);
    const float* w = ty ? w1f : w1s;
    (ty ? pw1f : pw1s)[idx] = f2b(w[k * 128 + c]);
  } else if (i < 98304) { // pW2 (2 types x 16384): [128][128]
    int i2 = i - 65536;
    int ty = i2 >> 14, idx = i2 & 16383;
    int j = idx & 7, l = (idx >> 3) & 63, kn = idx >> 9;
    int ks = kn & 3, nt = kn >> 2;
    int k = ks * 32 + (l >> 4) * 8 + j, c = nt * 16 + (l & 15);
    const float* w = ty ? w2f : w2s;
    (ty ? pw2f : pw2s)[idx] = f2b(w[k * 128 + c]);
  } else if (i < 98304 + 131072) { // pGRU: B[256][512] with zero blocks
    int idx = i - 98304;
    int j = idx & 7, l = (idx >> 3) & 63, kc = idx >> 9;
    int ks = kc & 7, ct = kc >> 3;
    int k = ks * 32 + (l >> 4) * 8 + j, c = ct * 16 + (l & 15);
    float v;
    if (c < 256)      v = (k < 128) ? gwih[c * 128 + k] : gwhh[c * 128 + (k - 128)];
    else if (c < 384) v = (k < 128) ? gwih[c * 128 + k] : 0.f;  // gi_n part
    else              v = (k >= 128) ? gwhh[(c - 128) * 128 + (k - 128)] : 0.f; // gh_n part
    pgru[idx] = f2b(v);
  } else if (i < 98304 + 131072 + 512) { // fused GRU biases
    int j = i - (98304 + 131072);
    float v;
    if (j < 256)      v = gbih[j] + gbhh[j]; // r and z: b_ih + b_hh
    else if (j < 384) v = gbih[j];           // gi_n bias
    else              v = gbhh[j - 128];     // gh_n bias
    bgr[j] = v;
  }
}

// ---------- histogram over key = type*NN + tgt ----------
__global__ __launch_bounds__(256) void k_hist(const int* __restrict__ ei, const int* __restrict__ et,
                                              int* __restrict__ hist) {
  int e = blockIdx.x * 256 + threadIdx.x; // grid exact
  int g = ei[EE + e];
  int ty = et[e];
  atomicAdd(&hist[ty * NN + g], 1);
}

// ---------- exclusive scan (3 kernels) ----------
__global__ __launch_bounds__(1024) void k_scan1(const int* __restrict__ hist, int* __restrict__ base,
                                                int* __restrict__ bsum) {
  __shared__ int sh[1024];
  int t = threadIdx.x;
  int i = blockIdx.x * 1024 + t;
  int v = (i < NBINS) ? hist[i] : 0;
  sh[t] = v;
  __syncthreads();
  for (int o = 1; o < 1024; o <<= 1) {
    int xv = (t >= o) ? sh[t - o] : 0;
    __syncthreads();
    sh[t] += xv;
    __syncthreads();
  }
  if (i < NBINS) base[i] = sh[t] - v;
  if (t == 1023) bsum[blockIdx.x] = sh[t];
}

__global__ __launch_bounds__(128) void k_scan2(int* __restrict__ bsum) {
  __shared__ int sh[128];
  int t = threadIdx.x;
  int v = (t < 98) ? bsum[t] : 0;
  sh[t] = v;
  __syncthreads();
  for (int o = 1; o < 128; o <<= 1) {
    int xv = (t >= o) ? sh[t - o] : 0;
    __syncthreads();
    sh[t] += xv;
    __syncthreads();
  }
  if (t < 98) bsum[t] = sh[t] - v;
}

__global__ __launch_bounds__(1024) void k_scan3(const int* __restrict__ bsum, int* __restrict__ base,
                                                int* __restrict__ cnt) {
  int i = blockIdx.x * 1024 + threadIdx.x;
  if (i < NBINS) {
    int b = base[i] + bsum[blockIdx.x];
    base[i] = b;
    if (i == NN) cnt[0] = b; // count of type-0 edges
  }
}

// ---------- scatter into sorted order ----------
__global__ __launch_bounds__(256) void k_scatter(const int* __restrict__ ei, const int* __restrict__ et,
                                                 int* __restrict__ woff, int* __restrict__ ssrc,
                                                 int* __restrict__ stgt) {
  int e = blockIdx.x * 256 + threadIdx.x; // grid exact
  int s = ei[e], g = ei[EE + e], ty = et[e];
  int pos = atomicAdd(&woff[ty * NN + g], 1);
  ssrc[pos] = s;
  stgt[pos] = g;
}

// ---------- edge MLP + segment scatter-add ----------
// tile = 64 edges, 256 threads / 4 waves. A-frag row = l&15, k = ks*32+(l>>4)*8+j.
// smem map: [0,16K) ef bf16 [64][128] swz(r&7)<<4, staged twice (src half / tgt half);
//           [16K,32K) hid bf16 [64][128] swz(r&7)<<4;
//           after GEMM2: [0,32K) m^T f32 [128 col][64 e] swz(col&15)<<4.
__global__ __launch_bounds__(256, 4) void k_edge(
    const unsigned short* __restrict__ hbf,
    const int* __restrict__ ssrc, const int* __restrict__ stgt,
    const unsigned short* __restrict__ pw1s, const unsigned short* __restrict__ pw2s,
    const unsigned short* __restrict__ pw1f, const unsigned short* __restrict__ pw2f,
    const float* __restrict__ b1s, const float* __restrict__ b2s,
    const float* __restrict__ b1f, const float* __restrict__ b2f,
    float* __restrict__ msg, const int* __restrict__ cnt) {
  __shared__ char smem[32768];
  __shared__ int tsrc[64];
  __shared__ int ttgt[64];
  char* efb = smem;
  char* hidb = smem + 16384;
  int tid = threadIdx.x;
  int l = tid & 63, w = tid >> 6;
  int c0 = cnt[0];
  int bid = blockIdx.x;
  int type = (bid >= NTILES) ? 1 : 0;
  int tb = type ? (bid - NTILES) : bid;
  int lo = type ? c0 : 0;
  int hi = type ? EE : c0;
  int start = lo + tb * 64;
  if (start >= hi) return;
  const unsigned short* pw1 = type ? pw1f : pw1s;
  const unsigned short* pw2 = type ? pw2f : pw2s;
  const float* b1 = type ? b1f : b1s;
  const float* b2 = type ? b2f : b2s;

  if (tid < 64) {
    int pp = start + tid;
    int s = 0, g = -1;
    if (pp < hi) { s = ssrc[pp]; g = stgt[pp]; }
    tsrc[tid] = (s < 0) ? 0 : s;
    ttgt[tid] = g;
  }
  __syncthreads();

  f32x4 zero4 = {0.f, 0.f, 0.f, 0.f};
  f32x4 acc[4][2];
#pragma unroll
  for (int mt = 0; mt < 4; mt++)
#pragma unroll
    for (int q = 0; q < 2; q++) acc[mt][q] = zero4;

  // GEMM1 in two K=128 halves: half0 = h[src] rows, half1 = h[tgt] rows
#pragma unroll
  for (int half = 0; half < 2; half++) {
    // stage 64 rows x 128 bf16 into efb
#pragma unroll
    for (int i = 0; i < 4; i++) {
      int c = tid + i * 256; // 1024 chunks = 64 rows x 16
      int r = c >> 4, cc = c & 15;
      int node;
      if (half == 0) node = tsrc[r];
      else { int gv = ttgt[r]; node = (gv < 0) ? 0 : gv; }
      int4 v = *((const int4*)(hbf + (size_t)node * HH) + cc);
      *(int4*)(efb + r * 256 + ((cc * 16) ^ ((r & 7) << 4))) = v;
    }
    __syncthreads();
    // B-frags for this K-half
    short8 bf1[2][4];
#pragma unroll
    for (int q = 0; q < 2; q++) {
      int nt = 2 * w + q;
#pragma unroll
      for (int ks = 0; ks < 4; ks++)
        bf1[q][ks] = *(const short8*)(pw1 + ((nt * 8 + half * 4 + ks) * 64 + l) * 8);
    }
#pragma unroll
    for (int ks = 0; ks < 4; ks++) {
      short8 a[4];
#pragma unroll
      for (int mt = 0; mt < 4; mt++) {
        int row = mt * 16 + (l & 15);
        a[mt] = *(const short8*)(efb + row * 256 + ((ks * 64 + (l >> 4) * 16) ^ ((row & 7) << 4)));
      }
#pragma unroll
      for (int mt = 0; mt < 4; mt++)
#pragma unroll
        for (int q = 0; q < 2; q++)
          acc[mt][q] = __builtin_amdgcn_mfma_f32_16x16x32_bf16(a[mt], bf1[q][ks], acc[mt][q], 0, 0, 0);
    }
    if (half == 0) __syncthreads(); // all reads of efb done before re-stage
  }

  // bias + relu -> hidden (bf16). C layout: col=(2w+q)*16+(l&15), row=mt*16+(l>>4)*4+r
  float b1v[2];
  b1v[0] = b1[(2 * w) * 16 + (l & 15)];
  b1v[1] = b1[(2 * w + 1) * 16 + (l & 15)];
#pragma unroll
  for (int mt = 0; mt < 4; mt++)
#pragma unroll
    for (int q = 0; q < 2; q++) {
      int col = (2 * w + q) * 16 + (l & 15);
#pragma unroll
      for (int r = 0; r < 4; r++) {
        int row = mt * 16 + (l >> 4) * 4 + r;
        float v = acc[mt][q][r] + b1v[q];
        v = v > 0.f ? v : 0.f;
        *(unsigned short*)(hidb + row * 256 + ((col * 2) ^ ((row & 7) << 4))) = f2b(v);
      }
    }
  __syncthreads();

  // GEMM2: hidden[64x128] @ W2[128x128]
  short8 bf2[2][4];
#pragma unroll
  for (int q = 0; q < 2; q++) {
    int nt = 2 * w + q;
#pragma unroll
    for (int ks = 0; ks < 4; ks++)
      bf2[q][ks] = *(const short8*)(pw2 + ((nt * 4 + ks) * 64 + l) * 8);
  }
  f32x4 acc2[4][2];
#pragma unroll
  for (int mt = 0; mt < 4; mt++)
#pragma unroll
    for (int q = 0; q < 2; q++) acc2[mt][q] = zero4;
#pragma unroll
  for (int ks = 0; ks < 4; ks++) {
    short8 a[4];
#pragma unroll
    for (int mt = 0; mt < 4; mt++) {
      int row = mt * 16 + (l & 15);
      a[mt] = *(const short8*)(hidb + row * 256 + ((ks * 64 + (l >> 4) * 16) ^ ((row & 7) << 4)));
    }
#pragma unroll
    for (int mt = 0; mt < 4; mt++)
#pragma unroll
      for (int q = 0; q < 2; q++)
        acc2[mt][q] = __builtin_amdgcn_mfma_f32_16x16x32_bf16(a[mt], bf2[q][ks], acc2[mt][q], 0, 0, 0);
  }
  __syncthreads(); // all GEMM2 reads done before m^T overwrites smem

  // m (+b2) -> LDS f32 m^T [128 col][64 e], one b128 per (mt,q)
  float b2v[2];
  b2v[0] = b2[(2 * w) * 16 + (l & 15)];
  b2v[1] = b2[(2 * w + 1) * 16 + (l & 15)];
#pragma unroll
  for (int mt = 0; mt < 4; mt++)
#pragma unroll
    for (int q = 0; q < 2; q++) {
      int col = (2 * w + q) * 16 + (l & 15);
      int e0 = mt * 16 + (l >> 4) * 4;
      f32x4 v = acc2[mt][q];
      v.x += b2v[q]; v.y += b2v[q]; v.z += b2v[q]; v.w += b2v[q];
      *(f32x4*)(smem + col * 256 + ((e0 * 4) ^ ((col & 15) << 4))) = v;
    }
  __syncthreads();

  // segment-reduce runs of equal tgt (tile sorted by tgt), vector LDS reads,
  // one atomicAdd per (run, feature)
  int f = tid & 127;
  int eb = (tid >> 7) * 32;
  float accum = 0.f;
  int cur = ttgt[eb];
#pragma unroll
  for (int j = 0; j < 8; j++) {
    f32x4 v = *(const f32x4*)(smem + f * 256 + (((eb + j * 4) * 4) ^ ((f & 15) << 4)));
#pragma unroll
    for (int r = 0; r < 4; r++) {
      int g = ttgt[eb + j * 4 + r];
      if (g != cur) {
        if (cur >= 0) atomicAdd(&msg[(size_t)cur * HH + f], accum);
        accum = 0.f;
        cur = g;
      }
      accum += v[r];
    }
  }
  if (cur >= 0) atomicAdd(&msg[(size_t)cur * HH + f], accum);
}

// ---------- GRU update: [m|h](64x256) @ B(256x512), col-tiles interleaved so r/z/gin/ghn share a lane
__global__ __launch_bounds__(256) void k_gru(
    const float* __restrict__ msg, const unsigned short* __restrict__ pgru,
    const float* __restrict__ bgr, float* __restrict__ h, unsigned short* __restrict__ hbf) {
  __shared__ char amh[64 * 512]; // [64][256] bf16 swz
  int tid = threadIdx.x, l = tid & 63, w = tid >> 6;
  int n0 = blockIdx.x * 64;
  // stage m (k 0..127), fp32 -> bf16
#pragma unroll
  for (int i = 0; i < 8; i++) {
    int c = tid + i * 256;
    int r = c >> 5, cc = c & 31;
    int node = n0 + r; if (node > NN - 1) node = NN - 1;
    float4 v = *((const float4*)(msg + (size_t)node * HH) + cc);
    uint2 u;
    u.x = (unsigned int)f2b(v.x) | ((unsigned int)f2b(v.y) << 16);
    u.y = (unsigned int)f2b(v.z) | ((unsigned int)f2b(v.w) << 16);
    *(uint2*)(amh + r * 512 + ((cc * 8) ^ ((r & 7) << 4))) = u;
  }
  // stage h (k 128..255), bf16 copy
#pragma unroll
  for (int i = 0; i < 4; i++) {
    int c = tid + i * 256;
    int r = c >> 4, cc = c & 15;
    int node = n0 + r; if (node > NN - 1) node = NN - 1;
    int4 v = *((const int4*)(hbf + (size_t)node * HH) + cc);
    *(int4*)(amh + r * 512 + ((256 + cc * 16) ^ ((r & 7) << 4))) = v;
  }
  __syncthreads();

  f32x4 zero4 = {0.f, 0.f, 0.f, 0.f};
  f32x4 acc[4][8];
#pragma unroll
  for (int mt = 0; mt < 4; mt++)
#pragma unroll
    for (int t = 0; t < 8; t++) acc[mt][t] = zero4;
#pragma unroll
  for (int ks = 0; ks < 8; ks++) {
    short8 a[4];
#pragma unroll
    for (int mt = 0; mt < 4; mt++) {
      int row = mt * 16 + (l & 15);
      a[mt] = *(const short8*)(amh + row * 512 + ((ks * 64 + (l >> 4) * 16) ^ ((row & 7) << 4)));
    }
#pragma unroll
    for (int t = 0; t < 8; t++) {
      int ct = w + 4 * t;
      short8 bf = *(const short8*)(pgru + ((ct * 8 + ks) * 64 + l) * 8);
#pragma unroll
      for (int mt = 0; mt < 4; mt++)
        acc[mt][t] = __builtin_amdgcn_mfma_f32_16x16x32_bf16(a[mt], bf, acc[mt][t], 0, 0, 0);
    }
  }

  // gates fully in-register: acc[.][tt]=u_r, [tt+2]=u_z, [tt+4]=gi_n, [tt+6]=gh_n
#pragma unroll
  for (int tt = 0; tt < 2; tt++) {
    int ct = w + 4 * tt;
    int j = ct * 16 + (l & 15);
    float br = bgr[j], bz = bgr[128 + j], bgi = bgr[256 + j], bgh = bgr[384 + j];
#pragma unroll
    for (int mt = 0; mt < 4; mt++) {
#pragma unroll
      for (int r = 0; r < 4; r++) {
        int row = mt * 16 + (l >> 4) * 4 + r;
        int node = n0 + row;
        if (node < NN) {
          float hold = h[(size_t)node * HH + j];
          float ur = acc[mt][tt][r] + br;
          float uz = acc[mt][tt + 2][r] + bz;
          float gi = acc[mt][tt + 4][r] + bgi;
          float gh = acc[mt][tt + 6][r] + bgh;
          float rr = 1.f / (1.f + __expf(-ur));
          float zz = 1.f / (1.f + __expf(-uz));
          float xx = gi + rr * gh;
          xx = fminf(fmaxf(xx, -15.f), 15.f);
          float ex = __expf(2.f * xx);
          float nn2 = (ex - 1.f) / (ex + 1.f); // tanh
          float hn = (1.f - zz) * nn2 + zz * hold;
          h[(size_t)node * HH + j] = hn;
          hbf[(size_t)node * HH + j] = f2b(hn);
        }
      }
    }
  }
}

// ---------- readout: softmax(relu(h@wr1+br1)@wr2+br2), vector fp32 ----------
__global__ __launch_bounds__(256) void k_read(const float* __restrict__ h,
                                              const float* __restrict__ wr1, const float* __restrict__ br1,
                                              const float* __restrict__ wr2, const float* __restrict__ br2,
                                              float* __restrict__ out) {
  __shared__ float sh[16][128];
  int tid = threadIdx.x, l = tid & 63, w = tid >> 6;
  int nb = blockIdx.x * 16;
#pragma unroll
  for (int i = 0; i < 8; i++) {
    int c = tid + i * 256;
    int r = c >> 7, k = c & 127;
    int node = nb + r; if (node > NN - 1) node = NN - 1;
    sh[r][k] = h[(size_t)node * HH + k];
  }
  __syncthreads();
  float a1[4] = {0.f, 0.f, 0.f, 0.f}, a2[4] = {0.f, 0.f, 0.f, 0.f};
  for (int k = 0; k < 128; k++) {
    float w1a = wr1[k * 128 + l];
    float w1b = wr1[k * 128 + l + 64];
#pragma unroll
    for (int n = 0; n < 4; n++) {
      float hv = sh[w * 4 + n][k];
      a1[n] += hv * w1a;
      a2[n] += hv * w1b;
    }
  }
  float bra = br1[l], brb = br1[l + 64];
  float w20 = wr2[l * 2 + 0], w21 = wr2[l * 2 + 1];
  float w20b = wr2[(l + 64) * 2 + 0], w21b = wr2[(l + 64) * 2 + 1];
#pragma unroll
  for (int n = 0; n < 4; n++) {
    float h1 = fmaxf(a1[n] + bra, 0.f), h2 = fmaxf(a2[n] + brb, 0.f);
    float l0 = h1 * w20 + h2 * w20b;
    float l1 = h1 * w21 + h2 * w21b;
#pragma unroll
    for (int o = 32; o > 0; o >>= 1) {
      l0 += __shfl_xor(l0, o);
      l1 += __shfl_xor(l1, o);
    }
    if (l == 0) {
      int node = nb + w * 4 + n;
      if (node < NN) {
        l0 += br2[0];
        l1 += br2[1];
        float mx = fmaxf(l0, l1);
        float e0 = __expf(l0 - mx), e1 = __expf(l1 - mx);
        float s = e0 + e1;
        out[node * 2 + 0] = e0 / s;
        out[node * 2 + 1] = e1 / s;
      }
    }
  }
}

extern "C" void kernel_launch(void* const* d_in, const int* in_sizes, int n_in,
                              void* d_out, int out_size, void* d_ws, size_t ws_size,
                              hipStream_t stream) {
  const float* x    = (const float*)d_in[0];
  const int*   ei   = (const int*)d_in[1];
  const int*   et   = (const int*)d_in[2];
  const float* w1s  = (const float*)d_in[3];
  const float* b1s  = (const float*)d_in[4];
  const float* w2s  = (const float*)d_in[5];
  const float* b2s  = (const float*)d_in[6];
  const float* w1f  = (const float*)d_in[7];
  const float* b1f  = (const float*)d_in[8];
  const float* w2f  = (const float*)d_in[9];
  const float* b2f  = (const float*)d_in[10];
  const float* gwih = (const float*)d_in[11];
  const float* gwhh = (const float*)d_in[12];
  const float* gbih = (const float*)d_in[13];
  const float* gbhh = (const float*)d_in[14];
  const float* wr1  = (const float*)d_in[15];
  const float* br1  = (const float*)d_in[16];
  const float* wr2  = (const float*)d_in[17];
  const float* br2  = (const float*)d_in[18];
  float* out = (float*)d_out;
  (void)in_sizes; (void)n_in; (void)out_size; (void)ws_size;

  char* p = (char*)d_ws;
  size_t off = 0;
  auto alloc = [&](size_t sz) {
    char* r = p + off;
    off = (off + sz + 255) & ~(size_t)255;
    return r;
  };
  float* h             = (float*)alloc((size_t)NN * HH * 4);
  unsigned short* hbf  = (unsigned short*)alloc((size_t)NN * HH * 2);
  float* msg           = (float*)alloc((size_t)NN * HH * 4);
  int* ssrc            = (int*)alloc((size_t)(EE + 64) * 4);
  int* stgt            = (int*)alloc((size_t)(EE + 64) * 4);
  int* hist            = (int*)alloc((size_t)NBINS * 4);
  int* base            = (int*)alloc((size_t)NBINS * 4);
  int* woff            = (int*)alloc((size_t)NBINS * 4);
  int* bsum            = (int*)alloc(128 * 4);
  int* cnt             = (int*)alloc(16);
  unsigned short* pw1s = (unsigned short*)alloc(32768 * 2);
  unsigned short* pw2s = (unsigned short*)alloc(16384 * 2);
  unsigned short* pw1f = (unsigned short*)alloc(32768 * 2);
  unsigned short* pw2f = (unsigned short*)alloc(16384 * 2);
  unsigned short* pgru = (unsigned short*)alloc(131072 * 2);
  float* bgr           = (float*)alloc(512 * 4);

  hipMemsetAsync(hist, 0, (size_t)NBINS * 4, stream);
  k_init<<<NN * HH / 256, 256, 0, stream>>>(x, h, hbf);
  k_pack<<<898, 256, 0, stream>>>(w1s, w2s, w1f, w2f, gwih, gwhh, gbih, gbhh,
                                  pw1s, pw2s, pw1f, pw2f, pgru, bgr);
  k_hist<<<EE / 256, 256, 0, stream>>>(ei, et, hist);
  k_scan1<<<98, 1024, 0, stream>>>(hist, base, bsum);
  k_scan2<<<1, 128, 0, stream>>>(bsum);
  k_scan3<<<98, 1024, 0, stream>>>(bsum, base, cnt);
  hipMemcpyAsync(woff, base, (size_t)NBINS * 4, hipMemcpyDeviceToDevice, stream);
  k_scatter<<<EE / 256, 256, 0, stream>>>(ei, et, woff, ssrc, stgt);
  hipMemsetAsync(ssrc + EE, 0xFF, 64 * 4, stream); // pad sentinel (-1)
  hipMemsetAsync(stgt + EE, 0xFF, 64 * 4, stream);

  for (int layer = 0; layer < 3; layer++) {
    hipMemsetAsync(msg, 0, (size_t)NN * HH * 4, stream);
    k_edge<<<2 * NTILES, 256, 0, stream>>>(hbf, ssrc, stgt, pw1s, pw2s, pw1f, pw2f,
                                           b1s, b2s, b1f, b2f, msg, cnt);
    k_gru<<<(NN + 63) / 64, 256, 0, stream>>>(msg, pgru, bgr, h, hbf);
  }
  k_read<<<NN / 16, 256, 0, stream>>>(h, wr1, br1, wr2, br2, out);
}

// Round 3
// 575.826 us; speedup vs baseline: 1.3138x; 1.0853x over previous
//
#include <hip/hip_runtime.h>
#include <hip/hip_bf16.h>

// CustomGNN on MI355X. Pipeline per call:
//   sort edges by (type, tgt) -> 3x [edge-MLP (bf16 MFMA) + scatter-add + GRU (bf16 MFMA)] -> readout.
// R3: persistent-block k_edge — weights in VGPRs (loaded once per block),
//     global_load_lds gather with pre-swizzled source, 1-tile-ahead prefetch
//     across raw s_barriers (counted by issue order + vmcnt(0)), bf16 m^T epilogue.

#define NN 50000
#define EE 640000
#define HH 128
#define NBINS (2 * NN)

typedef __attribute__((ext_vector_type(8))) short short8;
typedef __attribute__((ext_vector_type(4))) float f32x4;

__device__ __forceinline__ unsigned short f2b(float f) {
  __hip_bfloat16 b = __float2bfloat16(f);
  return *reinterpret_cast<unsigned short*>(&b);
}
__device__ __forceinline__ float b2f_lo(unsigned int u) {
  union { unsigned int u; float f; } a; a.u = u << 16; return a.f;
}
__device__ __forceinline__ float b2f_hi(unsigned int u) {
  union { unsigned int u; float f; } a; a.u = u & 0xFFFF0000u; return a.f;
}

__device__ __forceinline__ void gload_lds16(const void* g, void* l) {
  __builtin_amdgcn_global_load_lds((const __attribute__((address_space(1))) void*)g,
                                   (__attribute__((address_space(3))) void*)l, 16, 0, 0);
}

// ---------- init: h = x (fp32) and bf16 mirror ----------
__global__ __launch_bounds__(256) void k_init(const float* __restrict__ x, float* __restrict__ h,
                                              unsigned short* __restrict__ hbf) {
  int i = blockIdx.x * 256 + threadIdx.x; // grid exact
  float v = x[i];
  h[i] = v;
  hbf[i] = f2b(v);
}

// ---------- pack weights into MFMA B-fragment order (bf16) ----------
// B-frag (16x16x32): lane l holds B[k = ks*32 + (l>>4)*8 + j][col = nt*16 + (l&15)], j=0..7
__global__ __launch_bounds__(256) void k_pack(
    const float* __restrict__ w1s, const float* __restrict__ w2s,
    const float* __restrict__ w1f, const float* __restrict__ w2f,
    const float* __restrict__ gwih, const float* __restrict__ gwhh,
    const float* __restrict__ gbih, const float* __restrict__ gbhh,
    unsigned short* __restrict__ pw1s, unsigned short* __restrict__ pw2s,
    unsigned short* __restrict__ pw1f, unsigned short* __restrict__ pw2f,
    unsigned short* __restrict__ pgru, float* __restrict__ bgr) {
  int i = blockIdx.x * 256 + threadIdx.x;
  if (i < 65536) { // pW1 (2 types x 32768): [256][128]
    int ty = i >> 15, idx = i & 32767;
    int j = idx & 7, l = (idx >> 3) & 63, kn = idx >> 9;
    int ks = kn & 7, nt = kn >> 3;
    int k = ks * 32 + (l >> 4) * 8 + j, c = nt * 16 + (l & 15);
    const float* w = ty ? w1f : w1s;
    (ty ? pw1f : pw1s)[idx] = f2b(w[k * 128 + c]);
  } else if (i < 98304) { // pW2 (2 types x 16384): [128][128]
    int i2 = i - 65536;
    int ty = i2 >> 14, idx = i2 & 16383;
    int j = idx & 7, l = (idx >> 3) & 63, kn = idx >> 9;
    int ks = kn & 3, nt = kn >> 2;
    int k = ks * 32 + (l >> 4) * 8 + j, c = nt * 16 + (l & 15);
    const float* w = ty ? w2f : w2s;
    (ty ? pw2f : pw2s)[idx] = f2b(w[k * 128 + c]);
  } else if (i < 98304 + 131072) { // pGRU: B[256][512] with zero blocks
    int idx = i - 98304;
    int j = idx & 7, l = (idx >> 3) & 63, kc = idx >> 9;
    int ks = kc & 7, ct = kc >> 3;
    int k = ks * 32 + (l >> 4) * 8 + j, c = ct * 16 + (l & 15);
    float v;
    if (c < 256)      v = (k < 128) ? gwih[c * 128 + k] : gwhh[c * 128 + (k - 128)];
    else if (c < 384) v = (k < 128) ? gwih[c * 128 + k] : 0.f;  // gi_n part
    else              v = (k >= 128) ? gwhh[(c - 128) * 128 + (k - 128)] : 0.f; // gh_n part
    pgru[idx] = f2b(v);
  } else if (i < 98304 + 131072 + 512) { // fused GRU biases
    int j = i - (98304 + 131072);
    float v;
    if (j < 256)      v = gbih[j] + gbhh[j]; // r and z: b_ih + b_hh
    else if (j < 384) v = gbih[j];           // gi_n bias
    else              v = gbhh[j - 128];     // gh_n bias
    bgr[j] = v;
  }
}

// ---------- histogram over key = type*NN + tgt ----------
__global__ __launch_bounds__(256) void k_hist(const int* __restrict__ ei, const int* __restrict__ et,
                                              int* __restrict__ hist) {
  int e = blockIdx.x * 256 + threadIdx.x; // grid exact
  int g = ei[EE + e];
  int ty = et[e];
  atomicAdd(&hist[ty * NN + g], 1);
}

// ---------- exclusive scan (3 kernels) ----------
__global__ __launch_bounds__(1024) void k_scan1(const int* __restrict__ hist, int* __restrict__ base,
                                                int* __restrict__ bsum) {
  __shared__ int sh[1024];
  int t = threadIdx.x;
  int i = blockIdx.x * 1024 + t;
  int v = (i < NBINS) ? hist[i] : 0;
  sh[t] = v;
  __syncthreads();
  for (int o = 1; o < 1024; o <<= 1) {
    int xv = (t >= o) ? sh[t - o] : 0;
    __syncthreads();
    sh[t] += xv;
    __syncthreads();
  }
  if (i < NBINS) base[i] = sh[t] - v;
  if (t == 1023) bsum[blockIdx.x] = sh[t];
}

__global__ __launch_bounds__(128) void k_scan2(int* __restrict__ bsum) {
  __shared__ int sh[128];
  int t = threadIdx.x;
  int v = (t < 98) ? bsum[t] : 0;
  sh[t] = v;
  __syncthreads();
  for (int o = 1; o < 128; o <<= 1) {
    int xv = (t >= o) ? sh[t - o] : 0;
    __syncthreads();
    sh[t] += xv;
    __syncthreads();
  }
  if (t < 98) bsum[t] = sh[t] - v;
}

__global__ __launch_bounds__(1024) void k_scan3(const int* __restrict__ bsum, int* __restrict__ base,
                                                int* __restrict__ cnt) {
  int i = blockIdx.x * 1024 + threadIdx.x;
  if (i < NBINS) {
    int b = base[i] + bsum[blockIdx.x];
    base[i] = b;
    if (i == NN) cnt[0] = b; // count of type-0 edges
  }
}

// ---------- scatter into sorted order ----------
__global__ __launch_bounds__(256) void k_scatter(const int* __restrict__ ei, const int* __restrict__ et,
                                                 int* __restrict__ woff, int* __restrict__ ssrc,
                                                 int* __restrict__ stgt) {
  int e = blockIdx.x * 256 + threadIdx.x; // grid exact
  int s = ei[e], g = ei[EE + e], ty = et[e];
  int pos = atomicAdd(&woff[ty * NN + g], 1);
  ssrc[pos] = s;
  stgt[pos] = g;
}

// ---------- edge MLP + segment scatter-add (persistent, pipelined) ----------
// 512 blocks: [0,256) type-0, [256,512) type-1; block handles tiles bsub+k*256.
// Per tile (64 edges): gathers prefetched 1 tile ahead via global_load_lds
// (pre-swizzled source, linear LDS dest); indices prefetched 2 ahead.
// LDS: efA/efB = [64 rows][128 bf16] swz ((r&7)<<4); mC = hid [64][256B] swz,
// then m^T bf16 [128 col][stride 144B]. Raw s_barrier + manual waits.
__global__ __launch_bounds__(256, 2) void k_edge(
    const unsigned short* __restrict__ hbf,
    const int* __restrict__ ssrc, const int* __restrict__ stgt,
    const unsigned short* __restrict__ pw1s, const unsigned short* __restrict__ pw2s,
    const unsigned short* __restrict__ pw1f, const unsigned short* __restrict__ pw2f,
    const float* __restrict__ b1s, const float* __restrict__ b2s,
    const float* __restrict__ b1f, const float* __restrict__ b2f,
    float* __restrict__ msg, const int* __restrict__ cnt) {
  __shared__ char efA[16384];
  __shared__ char efB[16384];
  __shared__ char mC[18432];
  __shared__ int idxbuf[2][2][64]; // [slot][0=src,1=tgt][edge]
  const int tid = threadIdx.x, l = tid & 63, w = tid >> 6;
  const int c0 = cnt[0];
  const int type = blockIdx.x >> 8;
  const int bsub = blockIdx.x & 255;
  const int lo = type ? c0 : 0;
  const int hi = type ? EE : c0;
  const int ntile = (hi - lo + 63) >> 6;
  if (bsub >= ntile) return;
  const int nblk = 1 + (ntile - 1 - bsub) / 256;
  const unsigned short* pw1 = type ? pw1f : pw1s;
  const unsigned short* pw2 = type ? pw2f : pw2s;
  const float* b1 = type ? b1f : b1s;
  const float* b2 = type ? b2f : b2s;

  // persistent weights in VGPRs (per wave: col-tiles 2w, 2w+1)
  short8 wb1[2][8], wb2[2][4];
#pragma unroll
  for (int q = 0; q < 2; q++) {
    int nt = 2 * w + q;
#pragma unroll
    for (int ks = 0; ks < 8; ks++)
      wb1[q][ks] = *(const short8*)(pw1 + ((nt * 8 + ks) * 64 + l) * 8);
#pragma unroll
    for (int ks = 0; ks < 4; ks++)
      wb2[q][ks] = *(const short8*)(pw2 + ((nt * 4 + ks) * 64 + l) * 8);
  }
  float b1v[2], b2v[2];
  b1v[0] = b1[(2 * w) * 16 + (l & 15)];
  b1v[1] = b1[(2 * w + 1) * 16 + (l & 15)];
  b2v[0] = b2[(2 * w) * 16 + (l & 15)];
  b2v[1] = b2[(2 * w + 1) * 16 + (l & 15)];

  auto issue_gathers = [&](int slot) {
#pragma unroll
    for (int i = 0; i < 4; i++) {
      int r = w * 16 + i * 4 + (l >> 4);
      int j = (l & 15) ^ (r & 7); // pre-swizzled source chunk
      int nodeS = idxbuf[slot][0][r];
      gload_lds16(hbf + (size_t)nodeS * HH + j * 8, efA + w * 4096 + i * 1024);
      int nodeT = idxbuf[slot][1][r];
      if (nodeT < 0) nodeT = 0;
      gload_lds16(hbf + (size_t)nodeT * HH + j * 8, efB + w * 4096 + i * 1024);
    }
  };

  // warmup: stage idx(tile0) -> idxbuf[0]; prefetch idx(tile1) -> ridx
  {
    int p0 = lo + bsub * 64 + (tid & 63);
    if (tid < 64) {
      int v = (p0 < hi) ? ssrc[p0] : 0;
      if (v < 0) v = 0;
      idxbuf[0][0][tid] = v;
    } else if (tid < 128) {
      int v = (p0 < hi) ? stgt[p0] : -1;
      idxbuf[0][1][tid & 63] = v;
    }
  }
  int ridx = (tid < 64) ? 0 : -1;
  {
    int p1 = lo + (bsub + 256) * 64 + (tid & 63);
    if (tid < 128 && p1 < hi) ridx = (tid < 64) ? ssrc[p1] : stgt[p1];
  }
  asm volatile("s_waitcnt lgkmcnt(0)" ::: "memory");
  __builtin_amdgcn_s_barrier();
  issue_gathers(0);

  f32x4 zero4 = {0.f, 0.f, 0.f, 0.f};
  for (int k = 0; k < nblk; k++) {
    const int cur = k & 1, nxt = cur ^ 1;
    // A: gathers for this tile landed (they are the newest VMEM issued)
    asm volatile("s_waitcnt vmcnt(0)" ::: "memory");
    __builtin_amdgcn_sched_barrier(0);
    __builtin_amdgcn_s_barrier();

    // B: GEMM1 [64x256]@W1 -> hid
    f32x4 acc[4][2];
#pragma unroll
    for (int mt = 0; mt < 4; mt++)
#pragma unroll
      for (int q = 0; q < 2; q++) acc[mt][q] = zero4;
#pragma unroll
    for (int ks = 0; ks < 8; ks++) {
      const char* ef = (ks < 4) ? efA : efB;
      int ko = (ks & 3) * 64;
      short8 a[4];
#pragma unroll
      for (int mt = 0; mt < 4; mt++) {
        int row = mt * 16 + (l & 15);
        a[mt] = *(const short8*)(ef + row * 256 + ((ko + (l >> 4) * 16) ^ ((row & 7) << 4)));
      }
#pragma unroll
      for (int mt = 0; mt < 4; mt++)
#pragma unroll
        for (int q = 0; q < 2; q++)
          acc[mt][q] = __builtin_amdgcn_mfma_f32_16x16x32_bf16(a[mt], wb1[q][ks], acc[mt][q], 0, 0, 0);
    }
#pragma unroll
    for (int mt = 0; mt < 4; mt++)
#pragma unroll
      for (int q = 0; q < 2; q++) {
        int col = (2 * w + q) * 16 + (l & 15);
#pragma unroll
        for (int r = 0; r < 4; r++) {
          int row = mt * 16 + (l >> 4) * 4 + r;
          float v = acc[mt][q][r] + b1v[q];
          v = v > 0.f ? v : 0.f;
          *(unsigned short*)(mC + row * 256 + ((col * 2) ^ ((row & 7) << 4))) = f2b(v);
        }
      }
    // C: hid visible
    asm volatile("s_waitcnt lgkmcnt(0)" ::: "memory");
    __builtin_amdgcn_s_barrier();

    // D: GEMM2 hid[64x128]@W2
    f32x4 acc2[4][2];
#pragma unroll
    for (int mt = 0; mt < 4; mt++)
#pragma unroll
      for (int q = 0; q < 2; q++) acc2[mt][q] = zero4;
#pragma unroll
    for (int ks = 0; ks < 4; ks++) {
      short8 a[4];
#pragma unroll
      for (int mt = 0; mt < 4; mt++) {
        int row = mt * 16 + (l & 15);
        a[mt] = *(const short8*)(mC + row * 256 + ((ks * 64 + (l >> 4) * 16) ^ ((row & 7) << 4)));
      }
#pragma unroll
      for (int mt = 0; mt < 4; mt++)
#pragma unroll
        for (int q = 0; q < 2; q++)
          acc2[mt][q] = __builtin_amdgcn_mfma_f32_16x16x32_bf16(a[mt], wb2[q][ks], acc2[mt][q], 0, 0, 0);
    }
    // E: all GEMM2 reads of mC done
    __builtin_amdgcn_s_barrier();

    // F: m^T bf16 [128 col][64 e], stride 144B; + idxbuf[nxt] write; + ridx(t+2) load
#pragma unroll
    for (int mt = 0; mt < 4; mt++)
#pragma unroll
      for (int q = 0; q < 2; q++) {
        int col = (2 * w + q) * 16 + (l & 15);
        int e0 = mt * 16 + (l >> 4) * 4;
        f32x4 v = acc2[mt][q];
        unsigned int u0 = (unsigned int)f2b(v.x + b2v[q]) | ((unsigned int)f2b(v.y + b2v[q]) << 16);
        unsigned int u1 = (unsigned int)f2b(v.z + b2v[q]) | ((unsigned int)f2b(v.w + b2v[q]) << 16);
        uint2 uu; uu.x = u0; uu.y = u1;
        *(uint2*)(mC + col * 144 + e0 * 2) = uu;
      }
    if (tid < 128) {
      int v = ridx;
      if (tid < 64 && v < 0) v = 0;
      idxbuf[nxt][tid >= 64 ? 1 : 0][tid & 63] = v;
    }
    {
      int p2 = lo + (bsub + (k + 2) * 256) * 64 + (tid & 63);
      ridx = (tid < 64) ? 0 : -1;
      if (tid < 128 && p2 < hi) ridx = (tid < 64) ? ssrc[p2] : stgt[p2];
    }
    // G: m^T + idxbuf[nxt] visible
    asm volatile("s_waitcnt lgkmcnt(0)" ::: "memory");
    __builtin_amdgcn_s_barrier();

    // H: segment-reduce (sorted tgt) + atomics, then issue next tile's gathers LAST
    {
      int f = tid & 127, grp = tid >> 7;
      float accum = 0.f;
      int curg = idxbuf[cur][1][grp * 32];
#pragma unroll
      for (int jj = 0; jj < 8; jj++) {
        int4 tg = *(const int4*)&idxbuf[cur][1][grp * 32 + jj * 4];
        uint2 mv = *(const uint2*)(mC + f * 144 + (grp * 32 + jj * 4) * 2);
        float vv[4];
        vv[0] = b2f_lo(mv.x); vv[1] = b2f_hi(mv.x);
        vv[2] = b2f_lo(mv.y); vv[3] = b2f_hi(mv.y);
        int gg[4] = {tg.x, tg.y, tg.z, tg.w};
#pragma unroll
        for (int r = 0; r < 4; r++) {
          if (gg[r] != curg) {
            if (curg >= 0) atomicAdd(&msg[(size_t)curg * HH + f], accum);
            accum = 0.f;
            curg = gg[r];
          }
          accum += vv[r];
        }
      }
      if (curg >= 0) atomicAdd(&msg[(size_t)curg * HH + f], accum);
    }
    if (k + 1 < nblk) issue_gathers(nxt);
  }
}

// ---------- GRU update: [m|h](64x256) @ B(256x512), col-tiles interleaved so r/z/gin/ghn share a lane
__global__ __launch_bounds__(256) void k_gru(
    const float* __restrict__ msg, const unsigned short* __restrict__ pgru,
    const float* __restrict__ bgr, float* __restrict__ h, unsigned short* __restrict__ hbf) {
  __shared__ char amh[64 * 512]; // [64][256] bf16 swz
  int tid = threadIdx.x, l = tid & 63, w = tid >> 6;
  int n0 = blockIdx.x * 64;
  // stage m (k 0..127), fp32 -> bf16
#pragma unroll
  for (int i = 0; i < 8; i++) {
    int c = tid + i * 256;
    int r = c >> 5, cc = c & 31;
    int node = n0 + r; if (node > NN - 1) node = NN - 1;
    float4 v = *((const float4*)(msg + (size_t)node * HH) + cc);
    uint2 u;
    u.x = (unsigned int)f2b(v.x) | ((unsigned int)f2b(v.y) << 16);
    u.y = (unsigned int)f2b(v.z) | ((unsigned int)f2b(v.w) << 16);
    *(uint2*)(amh + r * 512 + ((cc * 8) ^ ((r & 7) << 4))) = u;
  }
  // stage h (k 128..255), bf16 copy
#pragma unroll
  for (int i = 0; i < 4; i++) {
    int c = tid + i * 256;
    int r = c >> 4, cc = c & 15;
    int node = n0 + r; if (node > NN - 1) node = NN - 1;
    int4 v = *((const int4*)(hbf + (size_t)node * HH) + cc);
    *(int4*)(amh + r * 512 + ((256 + cc * 16) ^ ((r & 7) << 4))) = v;
  }
  __syncthreads();

  f32x4 zero4 = {0.f, 0.f, 0.f, 0.f};
  f32x4 acc[4][8];
#pragma unroll
  for (int mt = 0; mt < 4; mt++)
#pragma unroll
    for (int t = 0; t < 8; t++) acc[mt][t] = zero4;
#pragma unroll
  for (int ks = 0; ks < 8; ks++) {
    short8 a[4];
#pragma unroll
    for (int mt = 0; mt < 4; mt++) {
      int row = mt * 16 + (l & 15);
      a[mt] = *(const short8*)(amh + row * 512 + ((ks * 64 + (l >> 4) * 16) ^ ((row & 7) << 4)));
    }
#pragma unroll
    for (int t = 0; t < 8; t++) {
      int ct = w + 4 * t;
      short8 bf = *(const short8*)(pgru + ((ct * 8 + ks) * 64 + l) * 8);
#pragma unroll
      for (int mt = 0; mt < 4; mt++)
        acc[mt][t] = __builtin_amdgcn_mfma_f32_16x16x32_bf16(a[mt], bf, acc[mt][t], 0, 0, 0);
    }
  }

  // gates fully in-register: acc[.][tt]=u_r, [tt+2]=u_z, [tt+4]=gi_n, [tt+6]=gh_n
#pragma unroll
  for (int tt = 0; tt < 2; tt++) {
    int ct = w + 4 * tt;
    int j = ct * 16 + (l & 15);
    float br = bgr[j], bz = bgr[128 + j], bgi = bgr[256 + j], bgh = bgr[384 + j];
#pragma unroll
    for (int mt = 0; mt < 4; mt++) {
#pragma unroll
      for (int r = 0; r < 4; r++) {
        int row = mt * 16 + (l >> 4) * 4 + r;
        int node = n0 + row;
        if (node < NN) {
          float hold = h[(size_t)node * HH + j];
          float ur = acc[mt][tt][r] + br;
          float uz = acc[mt][tt + 2][r] + bz;
          float gi = acc[mt][tt + 4][r] + bgi;
          float gh = acc[mt][tt + 6][r] + bgh;
          float rr = 1.f / (1.f + __expf(-ur));
          float zz = 1.f / (1.f + __expf(-uz));
          float xx = gi + rr * gh;
          xx = fminf(fmaxf(xx, -15.f), 15.f);
          float ex = __expf(2.f * xx);
          float nn2 = (ex - 1.f) / (ex + 1.f); // tanh
          float hn = (1.f - zz) * nn2 + zz * hold;
          h[(size_t)node * HH + j] = hn;
          hbf[(size_t)node * HH + j] = f2b(hn);
        }
      }
    }
  }
}

// ---------- readout: softmax(relu(h@wr1+br1)@wr2+br2), vector fp32 ----------
__global__ __launch_bounds__(256) void k_read(const float* __restrict__ h,
                                              const float* __restrict__ wr1, const float* __restrict__ br1,
                                              const float* __restrict__ wr2, const float* __restrict__ br2,
                                              float* __restrict__ out) {
  __shared__ float sh[16][128];
  int tid = threadIdx.x, l = tid & 63, w = tid >> 6;
  int nb = blockIdx.x * 16;
#pragma unroll
  for (int i = 0; i < 8; i++) {
    int c = tid + i * 256;
    int r = c >> 7, k = c & 127;
    int node = nb + r; if (node > NN - 1) node = NN - 1;
    sh[r][k] = h[(size_t)node * HH + k];
  }
  __syncthreads();
  float a1[4] = {0.f, 0.f, 0.f, 0.f}, a2[4] = {0.f, 0.f, 0.f, 0.f};
  for (int k = 0; k < 128; k++) {
    float w1a = wr1[k * 128 + l];
    float w1b = wr1[k * 128 + l + 64];
#pragma unroll
    for (int n = 0; n < 4; n++) {
      float hv = sh[w * 4 + n][k];
      a1[n] += hv * w1a;
      a2[n] += hv * w1b;
    }
  }
  float bra = br1[l], brb = br1[l + 64];
  float w20 = wr2[l * 2 + 0], w21 = wr2[l * 2 + 1];
  float w20b = wr2[(l + 64) * 2 + 0], w21b = wr2[(l + 64) * 2 + 1];
#pragma unroll
  for (int n = 0; n < 4; n++) {
    float h1 = fmaxf(a1[n] + bra, 0.f), h2 = fmaxf(a2[n] + brb, 0.f);
    float l0 = h1 * w20 + h2 * w20b;
    float l1 = h1 * w21 + h2 * w21b;
#pragma unroll
    for (int o = 32; o > 0; o >>= 1) {
      l0 += __shfl_xor(l0, o);
      l1 += __shfl_xor(l1, o);
    }
    if (l == 0) {
      int node = nb + w * 4 + n;
      if (node < NN) {
        l0 += br2[0];
        l1 += br2[1];
        float mx = fmaxf(l0, l1);
        float e0 = __expf(l0 - mx), e1 = __expf(l1 - mx);
        float s = e0 + e1;
        out[node * 2 + 0] = e0 / s;
        out[node * 2 + 1] = e1 / s;
      }
    }
  }
}

extern "C" void kernel_launch(void* const* d_in, const int* in_sizes, int n_in,
                              void* d_out, int out_size, void* d_ws, size_t ws_size,
                              hipStream_t stream) {
  const float* x    = (const float*)d_in[0];
  const int*   ei   = (const int*)d_in[1];
  const int*   et   = (const int*)d_in[2];
  const float* w1s  = (const float*)d_in[3];
  const float* b1s  = (const float*)d_in[4];
  const float* w2s  = (const float*)d_in[5];
  const float* b2s  = (const float*)d_in[6];
  const float* w1f  = (const float*)d_in[7];
  const float* b1f  = (const float*)d_in[8];
  const float* w2f  = (const float*)d_in[9];
  const float* b2f  = (const float*)d_in[10];
  const float* gwih = (const float*)d_in[11];
  const float* gwhh = (const float*)d_in[12];
  const float* gbih = (const float*)d_in[13];
  const float* gbhh = (const float*)d_in[14];
  const float* wr1  = (const float*)d_in[15];
  const float* br1  = (const float*)d_in[16];
  const float* wr2  = (const float*)d_in[17];
  const float* br2  = (const float*)d_in[18];
  float* out = (float*)d_out;
  (void)in_sizes; (void)n_in; (void)out_size; (void)ws_size;

  char* p = (char*)d_ws;
  size_t off = 0;
  auto alloc = [&](size_t sz) {
    char* r = p + off;
    off = (off + sz + 255) & ~(size_t)255;
    return r;
  };
  float* h             = (float*)alloc((size_t)NN * HH * 4);
  unsigned short* hbf  = (unsigned short*)alloc((size_t)NN * HH * 2);
  float* msg           = (float*)alloc((size_t)NN * HH * 4);
  int* ssrc            = (int*)alloc((size_t)EE * 4);
  int* stgt            = (int*)alloc((size_t)EE * 4);
  int* hist            = (int*)alloc((size_t)NBINS * 4);
  int* base            = (int*)alloc((size_t)NBINS * 4);
  int* woff            = (int*)alloc((size_t)NBINS * 4);
  int* bsum            = (int*)alloc(128 * 4);
  int* cnt             = (int*)alloc(16);
  unsigned short* pw1s = (unsigned short*)alloc(32768 * 2);
  unsigned short* pw2s = (unsigned short*)alloc(16384 * 2);
  unsigned short* pw1f = (unsigned short*)alloc(32768 * 2);
  unsigned short* pw2f = (unsigned short*)alloc(16384 * 2);
  unsigned short* pgru = (unsigned short*)alloc(131072 * 2);
  float* bgr           = (float*)alloc(512 * 4);

  hipMemsetAsync(hist, 0, (size_t)NBINS * 4, stream);
  k_init<<<NN * HH / 256, 256, 0, stream>>>(x, h, hbf);
  k_pack<<<898, 256, 0, stream>>>(w1s, w2s, w1f, w2f, gwih, gwhh, gbih, gbhh,
                                  pw1s, pw2s, pw1f, pw2f, pgru, bgr);
  k_hist<<<EE / 256, 256, 0, stream>>>(ei, et, hist);
  k_scan1<<<98, 1024, 0, stream>>>(hist, base, bsum);
  k_scan2<<<1, 128, 0, stream>>>(bsum);
  k_scan3<<<98, 1024, 0, stream>>>(bsum, base, cnt);
  hipMemcpyAsync(woff, base, (size_t)NBINS * 4, hipMemcpyDeviceToDevice, stream);
  k_scatter<<<EE / 256, 256, 0, stream>>>(ei, et, woff, ssrc, stgt);

  for (int layer = 0; layer < 3; layer++) {
    hipMemsetAsync(msg, 0, (size_t)NN * HH * 4, stream);
    k_edge<<<512, 256, 0, stream>>>(hbf, ssrc, stgt, pw1s, pw2s, pw1f, pw2f,
                                    b1s, b2s, b1f, b2f, msg, cnt);
    k_gru<<<(NN + 63) / 64, 256, 0, stream>>>(msg, pgru, bgr, h, hbf);
  }
  k_read<<<NN / 16, 256, 0, stream>>>(h, wr1, br1, wr2, br2, out);
}